// Round 3
// baseline (597.026 us; speedup 1.0000x reference)
//
#include <hip/hip_runtime.h>
#include <hip/hip_bf16.h>

typedef __bf16 bf16;
typedef __attribute__((ext_vector_type(8))) __bf16 bf16x8;
typedef __attribute__((ext_vector_type(4))) float f32x4;

#define D_MODEL 1024
#define NHEADS  16
#define DK      64
#define DFF     4096
#define BATCH   4
#define SEQ     2048
#define NTOK    (BATCH*SEQ)   // 8192
#define QSCALE  0.18033688011112042f   // 0.125 * log2(e)

__device__ __forceinline__ void gload16(const bf16* g, bf16* l) {
    __builtin_amdgcn_global_load_lds((const __attribute__((address_space(1))) void*)g,
                                     (__attribute__((address_space(3))) void*)l, 16, 0, 0);
}

// ---------------------------------------------------------------- transpose+cast
// W[K][N] fp32 -> Wt[N][K] bf16
__global__ __launch_bounds__(256) void transpose_cast(
    const float* __restrict__ W, bf16* __restrict__ Wt, int K, int N)
{
    __shared__ float tile[32][33];
    const int tx = threadIdx.x, ty = threadIdx.y;
    const int n0 = blockIdx.x * 32, k0 = blockIdx.y * 32;
#pragma unroll
    for (int i = 0; i < 4; ++i)
        tile[ty + i*8][tx] = W[(size_t)(k0 + ty + i*8) * N + n0 + tx];
    __syncthreads();
#pragma unroll
    for (int i = 0; i < 4; ++i)
        Wt[(size_t)(n0 + ty + i*8) * K + k0 + tx] = (bf16)tile[tx][ty + i*8];
}

// ---------------------------------------------------------------- V head-transpose
// Vh[bh][s][64] -> VhT[bh][64][2048]
__global__ __launch_bounds__(256) void transpose_v(
    const bf16* __restrict__ V, bf16* __restrict__ VT)
{
    __shared__ bf16 t[64][72];
    const int bh = blockIdx.y;
    const int s0 = blockIdx.x * 64;
    const int r  = threadIdx.x >> 2;         // 0..63
    const int c0 = (threadIdx.x & 3) * 16;   // 0,16,32,48
    const bf16* Vb = V  + (size_t)bh * SEQ * DK;
    bf16*       Tb = VT + (size_t)bh * DK * SEQ;
#pragma unroll
    for (int i = 0; i < 2; ++i) {
        bf16x8 v = *(const bf16x8*)&Vb[(size_t)(s0 + r) * DK + c0 + i*8];
#pragma unroll
        for (int j = 0; j < 8; ++j) t[c0 + i*8 + j][r] = v[j];
    }
    __syncthreads();
#pragma unroll
    for (int i = 0; i < 2; ++i) {
        bf16x8 o;
#pragma unroll
        for (int j = 0; j < 8; ++j) o[j] = t[r][c0 + i*8 + j];
        *(bf16x8*)&Tb[(size_t)r * SEQ + s0 + c0 + i*8] = o;
    }
}

// ---------------------------------------------------------------- layernorm (fp32 in, bf16 out)
__global__ __launch_bounds__(256) void ln_kernel(
    const float* __restrict__ x, const float* __restrict__ g,
    const float* __restrict__ beta, bf16* __restrict__ out)
{
    const int row = blockIdx.x, tid = threadIdx.x;
    const f32x4* xr = (const f32x4*)(x + (size_t)row * D_MODEL);
    f32x4 v = xr[tid];
    float s  = v[0] + v[1] + v[2] + v[3];
    float s2 = v[0]*v[0] + v[1]*v[1] + v[2]*v[2] + v[3]*v[3];
#pragma unroll
    for (int off = 32; off > 0; off >>= 1) {
        s  += __shfl_down(s,  off, 64);
        s2 += __shfl_down(s2, off, 64);
    }
    __shared__ float red[8];
    const int wave = tid >> 6, lane = tid & 63;
    if (lane == 0) { red[wave] = s; red[wave + 4] = s2; }
    __syncthreads();
    if (tid == 0) {
        float a = red[0] + red[1] + red[2] + red[3];
        float c = red[4] + red[5] + red[6] + red[7];
        float mu  = a * (1.0f / D_MODEL);
        float var = c * (1.0f / D_MODEL) - mu * mu;
        red[0] = mu;
        red[1] = rsqrtf(var + 1e-5f);
    }
    __syncthreads();
    const float mu = red[0], rs = red[1];
    f32x4 gv = ((const f32x4*)g)[tid];
    f32x4 bv = ((const f32x4*)beta)[tid];
    union { bf16 h[4]; uint2 u; } o;
#pragma unroll
    for (int i = 0; i < 4; ++i) o.h[i] = (bf16)((v[i] - mu) * rs * gv[i] + bv[i]);
    *(uint2*)(out + (size_t)row * D_MODEL + tid * 4) = o.u;
}

// ---------------------------------------------------------------- bf16 GEMM, 128x128 tile, BK=32
// A[M][K] bf16, Bt[N][K] bf16 (= B^T), C = A·B + bias (+epilogue)
// EPI 0: fused QKV: bias from {bias,bias2,bias3} by col segment; Q pre-scaled by QSCALE;
//        head-scatter bf16 out[seg][bh][s][dk] (Qh/Kh/Vh contiguous)
// EPI 1: fp32 out = acc + bias + resid      (O-proj, FFN2)
// EPI 2: bf16 out = relu(acc + bias)        (FFN1)
template<int EPI>
__global__ __launch_bounds__(256, 2) void gemm_bf16(
    const bf16* __restrict__ A, const bf16* __restrict__ Bt,
    const float* __restrict__ bias, const float* __restrict__ bias2,
    const float* __restrict__ bias3, const float* __restrict__ resid,
    void* __restrict__ outp, int M, int N, int K)
{
    __shared__ __align__(16) bf16 As[128 * 32];
    __shared__ __align__(16) bf16 Bs[128 * 32];
    const int tid  = threadIdx.x;
    const int wave = tid >> 6, lane = tid & 63;
    const int quad = lane >> 4, l16 = lane & 15;
    const int wr = wave >> 1, wc = wave & 1;
    const int m0 = blockIdx.y * 128, n0 = blockIdx.x * 128;

    const int r0 = wave * 32 + (lane >> 2);
    const int r1 = r0 + 16;
    const int u0 = ((lane & 3) - ((r0 >> 1) & 3)) & 3;
    const int u1 = ((lane & 3) - ((r1 >> 1) & 3)) & 3;
    const bf16* gA0 = A  + (size_t)(m0 + r0) * K + u0 * 8;
    const bf16* gA1 = A  + (size_t)(m0 + r1) * K + u1 * 8;
    const bf16* gB0 = Bt + (size_t)(n0 + r0) * K + u0 * 8;
    const bf16* gB1 = Bt + (size_t)(n0 + r1) * K + u1 * 8;
    bf16* lA0 = As + wave * 1024;
    bf16* lA1 = As + wave * 1024 + 512;
    bf16* lB0 = Bs + wave * 1024;
    bf16* lB1 = Bs + wave * 1024 + 512;

    int aoff[4], boff[4];
#pragma unroll
    for (int i = 0; i < 4; ++i) {
        const int ra = wr * 64 + i * 16 + l16;
        aoff[i] = ra * 32 + ((quad + ((ra >> 1) & 3)) & 3) * 8;
        const int rb = wc * 64 + i * 16 + l16;
        boff[i] = rb * 32 + ((quad + ((rb >> 1) & 3)) & 3) * 8;
    }

    const f32x4 vzero = {0.f, 0.f, 0.f, 0.f};
    f32x4 acc[4][4];
#pragma unroll
    for (int i = 0; i < 4; ++i)
#pragma unroll
        for (int j = 0; j < 4; ++j) acc[i][j] = vzero;

    for (int k0 = 0; k0 < K; k0 += 32) {
        __syncthreads();
        gload16(gA0 + k0, lA0);
        gload16(gA1 + k0, lA1);
        gload16(gB0 + k0, lB0);
        gload16(gB1 + k0, lB1);
        __syncthreads();
        bf16x8 af[4], bfr[4];
#pragma unroll
        for (int i = 0; i < 4; ++i) af[i]  = *(const bf16x8*)&As[aoff[i]];
#pragma unroll
        for (int j = 0; j < 4; ++j) bfr[j] = *(const bf16x8*)&Bs[boff[j]];
#pragma unroll
        for (int i = 0; i < 4; ++i)
#pragma unroll
            for (int j = 0; j < 4; ++j)
                acc[i][j] = __builtin_amdgcn_mfma_f32_16x16x32_bf16(af[i], bfr[j], acc[i][j], 0, 0, 0);
    }

#pragma unroll
    for (int i = 0; i < 4; ++i) {
#pragma unroll
        for (int j = 0; j < 4; ++j) {
            const int col = n0 + wc * 64 + j * 16 + l16;
            float bcol, sc = 1.0f;
            if (EPI == 0) {
                const int seg = col >> 10;
                const float* bp = (seg == 0) ? bias : ((seg == 1) ? bias2 : bias3);
                bcol = bp[col & 1023];
                if (seg == 0) sc = QSCALE;
            } else {
                bcol = bias[col];
            }
#pragma unroll
            for (int r = 0; r < 4; ++r) {
                const int row = m0 + wr * 64 + i * 16 + quad * 4 + r;
                const float v = acc[i][j][r] + bcol;
                if (EPI == 0) {
                    const int bb = row >> 11, ss = row & (SEQ - 1);
                    const int hh = (col & 1023) >> 6, dd = col & (DK - 1);
                    const size_t seg = (size_t)(col >> 10);
                    ((bf16*)outp)[seg * 8388608 + (((size_t)(bb * NHEADS + hh)) * SEQ + ss) * DK + dd] = (bf16)(v * sc);
                } else if (EPI == 1) {
                    const size_t idx = (size_t)row * N + col;
                    ((float*)outp)[idx] = v + resid[idx];
                } else {
                    ((bf16*)outp)[(size_t)row * N + col] = (bf16)fmaxf(v, 0.f);
                }
            }
        }
    }
}

// ---------------------------------------------------------------- flash attention (causal), S^T layout
// Q/K: [B*H][S][64] bf16 (Q pre-scaled by 0.125*log2e); VT: [B*H][64][S]; out: [B][S][H*64].
// Block = 4 waves = 128 q rows; pair (15-bx, bx) -> 17 kv-128 tiles per block.
// NO __syncthreads in the kv loop: kf/vf loaded directly global->VGPR (L1/L2-served),
// P^T round-trips through per-wave private LDS (same-wave lgkmcnt ordering only).
__global__ __launch_bounds__(256, 2) void attn_kernel(
    const bf16* __restrict__ Q, const bf16* __restrict__ K,
    const bf16* __restrict__ VT, bf16* __restrict__ out)
{
    const int bh = blockIdx.y;
    const int b = bh >> 4, h = bh & 15;
    const int tid  = threadIdx.x;
    const int wave = tid >> 6, lane = tid & 63;
    const int quad = lane >> 4, l16 = lane & 15;

    __shared__ __align__(16) bf16 Ps[4][32 * 136];   // per-wave P^T: [q=32][kv=128 pad 136]
    bf16* Pw = Ps[wave];

    const bf16* Qb = Q  + (size_t)bh * SEQ * DK;
    const bf16* Kb = K  + (size_t)bh * SEQ * DK;
    const bf16* Vb = VT + (size_t)bh * DK * SEQ;

    const f32x4 vzero = {0.f, 0.f, 0.f, 0.f};

    for (int half = 0; half < 2; ++half) {
        const int qt = half ? (int)blockIdx.x : 15 - (int)blockIdx.x;
        const int qw = qt * 128 + wave * 32;

        // Q fragments (B-operand: n=q=l16, k=d=quad*8+i)
        bf16x8 qf[2][2];
#pragma unroll
        for (int qi = 0; qi < 2; ++qi)
#pragma unroll
            for (int kk = 0; kk < 2; ++kk)
                qf[qi][kk] = *(const bf16x8*)&Qb[(size_t)(qw + qi*16 + l16) * DK + kk*32 + quad*8];

        f32x4 Oacc[2][4];
        float m_[2], l_[2];
#pragma unroll
        for (int qi = 0; qi < 2; ++qi) {
            m_[qi] = -1.0e30f; l_[qi] = 0.f;
#pragma unroll
            for (int dj = 0; dj < 4; ++dj) Oacc[qi][dj] = vzero;
        }

        for (int t = 0; t <= qt; ++t) {
            const int kv0 = t * 128;

            // S^T = K·Q^T, kf direct from global (A-operand: m=kv=l16(+16kvt), k=d)
            f32x4 sv[8][2];
#pragma unroll
            for (int kvt = 0; kvt < 8; ++kvt) {
                const bf16* krow = &Kb[(size_t)(kv0 + kvt*16 + l16) * DK + quad*8];
                bf16x8 kf0 = *(const bf16x8*)krow;
                bf16x8 kf1 = *(const bf16x8*)(krow + 32);
#pragma unroll
                for (int qi = 0; qi < 2; ++qi) {
                    f32x4 tacc = vzero;
                    tacc = __builtin_amdgcn_mfma_f32_16x16x32_bf16(kf0, qf[qi][0], tacc, 0, 0, 0);
                    tacc = __builtin_amdgcn_mfma_f32_16x16x32_bf16(kf1, qf[qi][1], tacc, 0, 0, 0);
                    sv[kvt][qi] = tacc;
                }
            }

            if (t == qt) {   // diagonal tile: causal mask (scores already scaled via Q)
#pragma unroll
                for (int kvt = 0; kvt < 8; ++kvt)
#pragma unroll
                    for (int qi = 0; qi < 2; ++qi)
#pragma unroll
                        for (int r = 0; r < 4; ++r) {
                            const int kv = kv0 + kvt*16 + quad*4 + r;
                            const int q  = qw + qi*16 + l16;
                            if (kv > q) sv[kvt][qi][r] = -1.0e30f;
                        }
            }

            // online softmax per q-column, base-2 domain
#pragma unroll
            for (int qi = 0; qi < 2; ++qi) {
                float mx = sv[0][qi][0];
#pragma unroll
                for (int kvt = 0; kvt < 8; ++kvt)
#pragma unroll
                    for (int r = 0; r < 4; ++r) mx = fmaxf(mx, sv[kvt][qi][r]);
                mx = fmaxf(mx, __shfl_xor(mx, 16, 64));
                mx = fmaxf(mx, __shfl_xor(mx, 32, 64));
                const float newm  = fmaxf(m_[qi], mx);
                const float alpha = exp2f(m_[qi] - newm);
                m_[qi] = newm;
                float rs = 0.f;
#pragma unroll
                for (int kvt = 0; kvt < 8; ++kvt)
#pragma unroll
                    for (int r = 0; r < 4; ++r) {
                        const float p = exp2f(sv[kvt][qi][r] - newm);
                        sv[kvt][qi][r] = p;
                        rs += p;
                    }
                rs += __shfl_xor(rs, 16, 64);
                rs += __shfl_xor(rs, 32, 64);
                l_[qi] = l_[qi] * alpha + rs;
#pragma unroll
                for (int dj = 0; dj < 4; ++dj) Oacc[qi][dj] *= alpha;
            }

            // P^T -> per-wave LDS (b64 packed writes), no barrier needed
#pragma unroll
            for (int qi = 0; qi < 2; ++qi)
#pragma unroll
                for (int kvt = 0; kvt < 8; ++kvt) {
                    union { bf16 h[4]; unsigned long long u; } pk;
#pragma unroll
                    for (int r = 0; r < 4; ++r) pk.h[r] = (bf16)sv[kvt][qi][r];
                    *(unsigned long long*)&Pw[(qi*16 + l16) * 136 + kvt*16 + quad*4] = pk.u;
                }

            // O^T += V^T · P^T, vf direct from global
#pragma unroll
            for (int c2 = 0; c2 < 4; ++c2) {
                bf16x8 vf[4];
#pragma unroll
                for (int dj = 0; dj < 4; ++dj)
                    vf[dj] = *(const bf16x8*)&Vb[(size_t)(dj*16 + l16) * SEQ + kv0 + c2*32 + quad*8];
#pragma unroll
                for (int qi = 0; qi < 2; ++qi) {
                    bf16x8 pf = *(const bf16x8*)&Pw[(qi*16 + l16) * 136 + c2*32 + quad*8];
#pragma unroll
                    for (int dj = 0; dj < 4; ++dj)
                        Oacc[qi][dj] = __builtin_amdgcn_mfma_f32_16x16x32_bf16(vf[dj], pf, Oacc[qi][dj], 0, 0, 0);
                }
            }
        }

        // epilogue: O^T C-layout -> token-major out
#pragma unroll
        for (int qi = 0; qi < 2; ++qi) {
            const float inv = 1.0f / l_[qi];
            const int q = qw + qi*16 + l16;
#pragma unroll
            for (int dj = 0; dj < 4; ++dj)
#pragma unroll
                for (int r = 0; r < 4; ++r) {
                    const int d = dj*16 + quad*4 + r;
                    out[((size_t)(b * SEQ + q)) * D_MODEL + h * DK + d] = (bf16)(Oacc[qi][dj][r] * inv);
                }
        }
    }
}

// ---------------------------------------------------------------- launch
extern "C" void kernel_launch(void* const* d_in, const int* in_sizes, int n_in,
                              void* d_out, int out_size, void* d_ws, size_t ws_size,
                              hipStream_t stream)
{
    const float* x    = (const float*)d_in[0];
    const float* Wq   = (const float*)d_in[1];
    const float* bq   = (const float*)d_in[2];
    const float* Wk   = (const float*)d_in[3];
    const float* bk   = (const float*)d_in[4];
    const float* Wv   = (const float*)d_in[5];
    const float* bv   = (const float*)d_in[6];
    const float* Wo   = (const float*)d_in[7];
    const float* bo   = (const float*)d_in[8];
    const float* W1   = (const float*)d_in[9];
    const float* b1   = (const float*)d_in[10];
    const float* W2   = (const float*)d_in[11];
    const float* b2   = (const float*)d_in[12];
    const float* ln1g = (const float*)d_in[13];
    const float* ln1b = (const float*)d_in[14];
    const float* ln2g = (const float*)d_in[15];
    const float* ln2b = (const float*)d_in[16];

    char* ws = (char*)d_ws;
    const size_t MB = 1024 * 1024;
    bf16* WTq  = (bf16*)(ws + 0 * MB);   // [1024][1024] — WTq/WTk/WTv contiguous = fused [3072][1024]
    bf16* WTk  = (bf16*)(ws + 2 * MB);
    bf16* WTv  = (bf16*)(ws + 4 * MB);
    bf16* WTo  = (bf16*)(ws + 6 * MB);
    bf16* WT1  = (bf16*)(ws + 8 * MB);   // [4096][1024]
    bf16* WT2  = (bf16*)(ws + 16 * MB);  // [1024][4096]
    bf16* hbuf = (bf16*)(ws + 24 * MB);  // h1; later h2
    bf16* VhT  = (bf16*)(ws + 24 * MB);  // aliases hbuf (h1 dead after QKV GEMM, VhT dead before LN2)
    bf16* Qh   = (bf16*)(ws + 40 * MB);  // [64][2048][64]; Kh/Vh contiguous after
    bf16* Kh   = (bf16*)(ws + 56 * MB);
    bf16* Vh   = (bf16*)(ws + 72 * MB);
    bf16* attn = (bf16*)(ws + 88 * MB);  // [8192][1024]
    bf16* ff1  = (bf16*)(ws + 40 * MB);  // aliases Qh/Kh/Vh/attn (free after O-proj)
    float* x2  = (float*)d_out;          // fp32 residual stream in d_out

    dim3 tb(32, 8);
    transpose_cast<<<dim3(32, 32),  tb, 0, stream>>>(Wq, WTq, 1024, 1024);
    transpose_cast<<<dim3(32, 32),  tb, 0, stream>>>(Wk, WTk, 1024, 1024);
    transpose_cast<<<dim3(32, 32),  tb, 0, stream>>>(Wv, WTv, 1024, 1024);
    transpose_cast<<<dim3(32, 32),  tb, 0, stream>>>(Wo, WTo, 1024, 1024);
    transpose_cast<<<dim3(128, 32), tb, 0, stream>>>(W1, WT1, 1024, 4096);
    transpose_cast<<<dim3(32, 128), tb, 0, stream>>>(W2, WT2, 4096, 1024);

    ln_kernel<<<NTOK, 256, 0, stream>>>(x, ln1g, ln1b, hbuf);

    // fused QKV: N=3072, Q pre-scaled by QSCALE in epilogue
    gemm_bf16<0><<<dim3(24, 64), 256, 0, stream>>>(hbuf, WTq, bq, bk, bv, nullptr, Qh, NTOK, 3072, 1024);

    transpose_v<<<dim3(32, 64), 256, 0, stream>>>(Vh, VhT);

    attn_kernel<<<dim3(8, 64), 256, 0, stream>>>(Qh, Kh, VhT, attn);

    gemm_bf16<1><<<dim3(8, 64), 256, 0, stream>>>(attn, WTo, bo, nullptr, nullptr, x, x2, NTOK, 1024, 1024);

    ln_kernel<<<NTOK, 256, 0, stream>>>(x2, ln2g, ln2b, hbuf);

    gemm_bf16<2><<<dim3(32, 64), 256, 0, stream>>>(hbuf, WT1, b1, nullptr, nullptr, nullptr, ff1, NTOK, 4096, 1024);
    gemm_bf16<1><<<dim3(8, 64),  256, 0, stream>>>(ff1, WT2, b2, nullptr, nullptr, x2, x2, NTOK, 1024, 4096);
}

// Round 4
// 554.362 us; speedup vs baseline: 1.0770x; 1.0770x over previous
//
#include <hip/hip_runtime.h>
#include <hip/hip_bf16.h>

typedef __bf16 bf16;
typedef __attribute__((ext_vector_type(8))) __bf16 bf16x8;
typedef __attribute__((ext_vector_type(4))) float f32x4;

#define D_MODEL 1024
#define NHEADS  16
#define DK      64
#define DFF     4096
#define BATCH   4
#define SEQ     2048
#define NTOK    (BATCH*SEQ)   // 8192
#define QSCALE  0.18033688011112042f   // 0.125 * log2(e)

__device__ __forceinline__ void gload16(const bf16* g, bf16* l) {
    __builtin_amdgcn_global_load_lds((const __attribute__((address_space(1))) void*)g,
                                     (__attribute__((address_space(3))) void*)l, 16, 0, 0);
}

// ---------------------------------------------------------------- transpose+cast
// W[K][N] fp32 -> Wt[N][K] bf16
__global__ __launch_bounds__(256) void transpose_cast(
    const float* __restrict__ W, bf16* __restrict__ Wt, int K, int N)
{
    __shared__ float tile[32][33];
    const int tx = threadIdx.x, ty = threadIdx.y;
    const int n0 = blockIdx.x * 32, k0 = blockIdx.y * 32;
#pragma unroll
    for (int i = 0; i < 4; ++i)
        tile[ty + i*8][tx] = W[(size_t)(k0 + ty + i*8) * N + n0 + tx];
    __syncthreads();
#pragma unroll
    for (int i = 0; i < 4; ++i)
        Wt[(size_t)(n0 + ty + i*8) * K + k0 + tx] = (bf16)tile[tx][ty + i*8];
}

// ---------------------------------------------------------------- V head-transpose
// Vh[bh][s][64] -> VhT[bh][64][2048]
__global__ __launch_bounds__(256) void transpose_v(
    const bf16* __restrict__ V, bf16* __restrict__ VT)
{
    __shared__ bf16 t[64][72];
    const int bh = blockIdx.y;
    const int s0 = blockIdx.x * 64;
    const int r  = threadIdx.x >> 2;         // 0..63
    const int c0 = (threadIdx.x & 3) * 16;   // 0,16,32,48
    const bf16* Vb = V  + (size_t)bh * SEQ * DK;
    bf16*       Tb = VT + (size_t)bh * DK * SEQ;
#pragma unroll
    for (int i = 0; i < 2; ++i) {
        bf16x8 v = *(const bf16x8*)&Vb[(size_t)(s0 + r) * DK + c0 + i*8];
#pragma unroll
        for (int j = 0; j < 8; ++j) t[c0 + i*8 + j][r] = v[j];
    }
    __syncthreads();
#pragma unroll
    for (int i = 0; i < 2; ++i) {
        bf16x8 o;
#pragma unroll
        for (int j = 0; j < 8; ++j) o[j] = t[r][c0 + i*8 + j];
        *(bf16x8*)&Tb[(size_t)r * SEQ + s0 + c0 + i*8] = o;
    }
}

// ---------------------------------------------------------------- layernorm (fp32 in, bf16 out)
__global__ __launch_bounds__(256) void ln_kernel(
    const float* __restrict__ x, const float* __restrict__ g,
    const float* __restrict__ beta, bf16* __restrict__ out)
{
    const int row = blockIdx.x, tid = threadIdx.x;
    const f32x4* xr = (const f32x4*)(x + (size_t)row * D_MODEL);
    f32x4 v = xr[tid];
    float s  = v[0] + v[1] + v[2] + v[3];
    float s2 = v[0]*v[0] + v[1]*v[1] + v[2]*v[2] + v[3]*v[3];
#pragma unroll
    for (int off = 32; off > 0; off >>= 1) {
        s  += __shfl_down(s,  off, 64);
        s2 += __shfl_down(s2, off, 64);
    }
    __shared__ float red[8];
    const int wave = tid >> 6, lane = tid & 63;
    if (lane == 0) { red[wave] = s; red[wave + 4] = s2; }
    __syncthreads();
    if (tid == 0) {
        float a = red[0] + red[1] + red[2] + red[3];
        float c = red[4] + red[5] + red[6] + red[7];
        float mu  = a * (1.0f / D_MODEL);
        float var = c * (1.0f / D_MODEL) - mu * mu;
        red[0] = mu;
        red[1] = rsqrtf(var + 1e-5f);
    }
    __syncthreads();
    const float mu = red[0], rs = red[1];
    f32x4 gv = ((const f32x4*)g)[tid];
    f32x4 bv = ((const f32x4*)beta)[tid];
    union { bf16 h[4]; uint2 u; } o;
#pragma unroll
    for (int i = 0; i < 4; ++i) o.h[i] = (bf16)((v[i] - mu) * rs * gv[i] + bv[i]);
    *(uint2*)(out + (size_t)row * D_MODEL + tid * 4) = o.u;
}

// ---------------------------------------------------------------- bf16 GEMM, 128x128 tile, BK=32
// A[M][K] bf16, Bt[N][K] bf16 (= B^T), C = A·B + bias (+epilogue)
// EPI 0: fused QKV: bias by col segment; Q pre-scaled by QSCALE; head-scatter out
// EPI 1: fp32 out = acc + bias + resid      (O-proj, FFN2)
// EPI 2: bf16 out = relu(acc + bias)        (FFN1)
template<int EPI>
__global__ __launch_bounds__(256, 2) void gemm_bf16(
    const bf16* __restrict__ A, const bf16* __restrict__ Bt,
    const float* __restrict__ bias, const float* __restrict__ bias2,
    const float* __restrict__ bias3, const float* __restrict__ resid,
    void* __restrict__ outp, int M, int N, int K)
{
    __shared__ __align__(16) bf16 As[128 * 32];
    __shared__ __align__(16) bf16 Bs[128 * 32];
    const int tid  = threadIdx.x;
    const int wave = tid >> 6, lane = tid & 63;
    const int quad = lane >> 4, l16 = lane & 15;
    const int wr = wave >> 1, wc = wave & 1;
    const int m0 = blockIdx.y * 128, n0 = blockIdx.x * 128;

    const int r0 = wave * 32 + (lane >> 2);
    const int r1 = r0 + 16;
    const int u0 = ((lane & 3) - ((r0 >> 1) & 3)) & 3;
    const int u1 = ((lane & 3) - ((r1 >> 1) & 3)) & 3;
    const bf16* gA0 = A  + (size_t)(m0 + r0) * K + u0 * 8;
    const bf16* gA1 = A  + (size_t)(m0 + r1) * K + u1 * 8;
    const bf16* gB0 = Bt + (size_t)(n0 + r0) * K + u0 * 8;
    const bf16* gB1 = Bt + (size_t)(n0 + r1) * K + u1 * 8;
    bf16* lA0 = As + wave * 1024;
    bf16* lA1 = As + wave * 1024 + 512;
    bf16* lB0 = Bs + wave * 1024;
    bf16* lB1 = Bs + wave * 1024 + 512;

    int aoff[4], boff[4];
#pragma unroll
    for (int i = 0; i < 4; ++i) {
        const int ra = wr * 64 + i * 16 + l16;
        aoff[i] = ra * 32 + ((quad + ((ra >> 1) & 3)) & 3) * 8;
        const int rb = wc * 64 + i * 16 + l16;
        boff[i] = rb * 32 + ((quad + ((rb >> 1) & 3)) & 3) * 8;
    }

    const f32x4 vzero = {0.f, 0.f, 0.f, 0.f};
    f32x4 acc[4][4];
#pragma unroll
    for (int i = 0; i < 4; ++i)
#pragma unroll
        for (int j = 0; j < 4; ++j) acc[i][j] = vzero;

    for (int k0 = 0; k0 < K; k0 += 32) {
        __syncthreads();
        gload16(gA0 + k0, lA0);
        gload16(gA1 + k0, lA1);
        gload16(gB0 + k0, lB0);
        gload16(gB1 + k0, lB1);
        __syncthreads();
        bf16x8 af[4], bfr[4];
#pragma unroll
        for (int i = 0; i < 4; ++i) af[i]  = *(const bf16x8*)&As[aoff[i]];
#pragma unroll
        for (int j = 0; j < 4; ++j) bfr[j] = *(const bf16x8*)&Bs[boff[j]];
#pragma unroll
        for (int i = 0; i < 4; ++i)
#pragma unroll
            for (int j = 0; j < 4; ++j)
                acc[i][j] = __builtin_amdgcn_mfma_f32_16x16x32_bf16(af[i], bfr[j], acc[i][j], 0, 0, 0);
    }

#pragma unroll
    for (int i = 0; i < 4; ++i) {
#pragma unroll
        for (int j = 0; j < 4; ++j) {
            const int col = n0 + wc * 64 + j * 16 + l16;
            float bcol, sc = 1.0f;
            if (EPI == 0) {
                const int seg = col >> 10;
                const float* bp = (seg == 0) ? bias : ((seg == 1) ? bias2 : bias3);
                bcol = bp[col & 1023];
                if (seg == 0) sc = QSCALE;
            } else {
                bcol = bias[col];
            }
#pragma unroll
            for (int r = 0; r < 4; ++r) {
                const int row = m0 + wr * 64 + i * 16 + quad * 4 + r;
                const float v = acc[i][j][r] + bcol;
                if (EPI == 0) {
                    const int bb = row >> 11, ss = row & (SEQ - 1);
                    const int hh = (col & 1023) >> 6, dd = col & (DK - 1);
                    const size_t seg = (size_t)(col >> 10);
                    ((bf16*)outp)[seg * 8388608 + (((size_t)(bb * NHEADS + hh)) * SEQ + ss) * DK + dd] = (bf16)(v * sc);
                } else if (EPI == 1) {
                    const size_t idx = (size_t)row * N + col;
                    ((float*)outp)[idx] = v + resid[idx];
                } else {
                    ((bf16*)outp)[(size_t)row * N + col] = (bf16)fmaxf(v, 0.f);
                }
            }
        }
    }
}

// ---------------------------------------------------------------- flash attention (causal), S^T layout
// Q/K: [B*H][S][64] bf16 (Q pre-scaled by 0.125*log2e); VT: [B*H][64][S]; out: [B][S][H*64].
// Grid (64 bh, 16): one 128-q tile per block, qt = 15 - by (long blocks dispatch first).
// bh on blockIdx.x -> all blocks of a bh land on one XCD (linear%8 = x%8): K/V L2-resident.
// K/V staged via async global_load_lds into XOR-swizzled unpadded LDS; P^T round-trips
// per-wave LDS in 32-kv chunks (same-wave lgkm ordering, no barrier in the chunk loop).
__global__ __launch_bounds__(256, 3) void attn_kernel(
    const bf16* __restrict__ Q, const bf16* __restrict__ K,
    const bf16* __restrict__ VT, bf16* __restrict__ out)
{
    const int bh = blockIdx.x;
    const int qt = 15 - (int)blockIdx.y;
    const int b = bh >> 4, h = bh & 15;
    const int tid  = threadIdx.x;
    const int wave = tid >> 6, lane = tid & 63;
    const int quad = lane >> 4, l16 = lane & 15;

    __shared__ __align__(16) bf16 smem[8192 + 8192 + 4 * 1280];
    bf16* Ks = smem;                            // [128 kv][8 units], unit-swizzled
    bf16* Vt = smem + 8192;                     // [64 d][16 units], unit-swizzled
    bf16* Pw = smem + 16384 + wave * 1280;      // per-wave [32 q][40]

    const bf16* Qb = Q  + (size_t)bh * SEQ * DK;
    const bf16* Kb = K  + (size_t)bh * SEQ * DK;
    const bf16* Vb = VT + (size_t)bh * DK * SEQ;

    // staging addresses: LDS linear unit U -> swizzled global unit
    int goK[4], goV[4];
    bf16 *lK[4], *lV[4];
#pragma unroll
    for (int i = 0; i < 4; ++i) {
        const int U = (wave * 4 + i) * 64 + lane;
        const int rK = U >> 3, uK = (U & 7) ^ (rK & 7);
        goK[i] = rK * DK + uK * 8;
        lK[i]  = Ks + (wave * 4 + i) * 512;
        const int rV = U >> 4, usw = U & 15;
        const int uV = (usw & 8) | ((usw & 7) ^ (rV & 7));
        goV[i] = rV * SEQ + uV * 8;
        lV[i]  = Vt + (wave * 4 + i) * 512;
    }

    const int qw = qt * 128 + wave * 32;

    // Q fragments (B-operand: n=q=l16, k=d=quad*8+i)
    bf16x8 qf[2][2];
#pragma unroll
    for (int qi = 0; qi < 2; ++qi)
#pragma unroll
        for (int kk = 0; kk < 2; ++kk)
            qf[qi][kk] = *(const bf16x8*)&Qb[(size_t)(qw + qi*16 + l16) * DK + kk*32 + quad*8];

    const f32x4 vzero = {0.f, 0.f, 0.f, 0.f};
    f32x4 Oacc[2][4];
    float m_[2], l_[2];
#pragma unroll
    for (int qi = 0; qi < 2; ++qi) {
        m_[qi] = -1.0e30f; l_[qi] = 0.f;
#pragma unroll
        for (int dj = 0; dj < 4; ++dj) Oacc[qi][dj] = vzero;
    }

    for (int t = 0; t <= qt; ++t) {
        const int kv0 = t * 128;
        __syncthreads();
#pragma unroll
        for (int i = 0; i < 4; ++i) gload16(Kb + (size_t)kv0 * DK + goK[i], lK[i]);
#pragma unroll
        for (int i = 0; i < 4; ++i) gload16(Vb + kv0 + goV[i], lV[i]);
        __syncthreads();

        // S^T = K·Q^T (A-operand kf from swizzled LDS)
        f32x4 sv[8][2];
#pragma unroll
        for (int kvt = 0; kvt < 8; ++kvt) {
            const int R = kvt*16 + l16, rx = R & 7;
            bf16x8 kf0 = *(const bf16x8*)&Ks[R*64 + (quad ^ rx)*8];
            bf16x8 kf1 = *(const bf16x8*)&Ks[R*64 + ((quad + 4) ^ rx)*8];
#pragma unroll
            for (int qi = 0; qi < 2; ++qi) {
                f32x4 tacc = vzero;
                tacc = __builtin_amdgcn_mfma_f32_16x16x32_bf16(kf0, qf[qi][0], tacc, 0, 0, 0);
                tacc = __builtin_amdgcn_mfma_f32_16x16x32_bf16(kf1, qf[qi][1], tacc, 0, 0, 0);
                sv[kvt][qi] = tacc;
            }
        }

        if (t == qt) {   // diagonal: causal mask (scores pre-scaled via Q)
#pragma unroll
            for (int kvt = 0; kvt < 8; ++kvt)
#pragma unroll
                for (int qi = 0; qi < 2; ++qi)
#pragma unroll
                    for (int r = 0; r < 4; ++r) {
                        const int kv = kv0 + kvt*16 + quad*4 + r;
                        const int q  = qw + qi*16 + l16;
                        if (kv > q) sv[kvt][qi][r] = -1.0e30f;
                    }
        }

        // online softmax per q-column, base-2
#pragma unroll
        for (int qi = 0; qi < 2; ++qi) {
            float mx = sv[0][qi][0];
#pragma unroll
            for (int kvt = 0; kvt < 8; ++kvt)
#pragma unroll
                for (int r = 0; r < 4; ++r) mx = fmaxf(mx, sv[kvt][qi][r]);
            mx = fmaxf(mx, __shfl_xor(mx, 16, 64));
            mx = fmaxf(mx, __shfl_xor(mx, 32, 64));
            const float newm  = fmaxf(m_[qi], mx);
            const float alpha = exp2f(m_[qi] - newm);
            m_[qi] = newm;
            float rs = 0.f;
#pragma unroll
            for (int kvt = 0; kvt < 8; ++kvt)
#pragma unroll
                for (int r = 0; r < 4; ++r) {
                    const float p = exp2f(sv[kvt][qi][r] - newm);
                    sv[kvt][qi][r] = p;
                    rs += p;
                }
            rs += __shfl_xor(rs, 16, 64);
            rs += __shfl_xor(rs, 32, 64);
            l_[qi] = l_[qi] * alpha + rs;
#pragma unroll
            for (int dj = 0; dj < 4; ++dj) Oacc[qi][dj] *= alpha;
        }

        // O^T += V^T·P^T in 32-kv chunks; P relayout via per-wave LDS
#pragma unroll
        for (int c2 = 0; c2 < 4; ++c2) {
#pragma unroll
            for (int qi = 0; qi < 2; ++qi)
#pragma unroll
                for (int kl = 0; kl < 2; ++kl) {
                    union { bf16 h[4]; unsigned long long u; } pk;
                    const f32x4 s = sv[c2*2 + kl][qi];
#pragma unroll
                    for (int r = 0; r < 4; ++r) pk.h[r] = (bf16)s[r];
                    *(unsigned long long*)&Pw[(qi*16 + l16)*40 + kl*16 + quad*4] = pk.u;
                }
            bf16x8 vf[4];
#pragma unroll
            for (int dj = 0; dj < 4; ++dj) {
                const int R = dj*16 + l16;
                const int u = c2*4 + quad;
                const int usw = (u & 8) | ((u & 7) ^ (R & 7));
                vf[dj] = *(const bf16x8*)&Vt[R*128 + usw*8];
            }
#pragma unroll
            for (int qi = 0; qi < 2; ++qi) {
                bf16x8 pf = *(const bf16x8*)&Pw[(qi*16 + l16)*40 + quad*8];
#pragma unroll
                for (int dj = 0; dj < 4; ++dj)
                    Oacc[qi][dj] = __builtin_amdgcn_mfma_f32_16x16x32_bf16(vf[dj], pf, Oacc[qi][dj], 0, 0, 0);
            }
        }
    }

    // epilogue: transpose O^T through per-wave LDS, b128 coalesced stores
    __syncthreads();   // all waves done reading Ks/Vt
    bf16* Ow = smem + wave * 2304;   // [32 q][72]
#pragma unroll
    for (int qi = 0; qi < 2; ++qi) {
        const float inv = 1.0f / l_[qi];
#pragma unroll
        for (int dj = 0; dj < 4; ++dj) {
            union { bf16 h[4]; unsigned long long u; } ok;
#pragma unroll
            for (int r = 0; r < 4; ++r) ok.h[r] = (bf16)(Oacc[qi][dj][r] * inv);
            *(unsigned long long*)&Ow[(qi*16 + l16)*72 + dj*16 + quad*4] = ok.u;
        }
    }
    const int rl = lane >> 3, ul = lane & 7;
#pragma unroll
    for (int i = 0; i < 4; ++i) {
        const int row = rl + i*8;
        const int q = qw + row;
        bf16x8 o = *(const bf16x8*)&Ow[row*72 + ul*8];
        *(bf16x8*)&out[((size_t)(b*SEQ + q))*D_MODEL + h*DK + ul*8] = o;
    }
}

// ---------------------------------------------------------------- launch
extern "C" void kernel_launch(void* const* d_in, const int* in_sizes, int n_in,
                              void* d_out, int out_size, void* d_ws, size_t ws_size,
                              hipStream_t stream)
{
    const float* x    = (const float*)d_in[0];
    const float* Wq   = (const float*)d_in[1];
    const float* bq   = (const float*)d_in[2];
    const float* Wk   = (const float*)d_in[3];
    const float* bk   = (const float*)d_in[4];
    const float* Wv   = (const float*)d_in[5];
    const float* bv   = (const float*)d_in[6];
    const float* Wo   = (const float*)d_in[7];
    const float* bo   = (const float*)d_in[8];
    const float* W1   = (const float*)d_in[9];
    const float* b1   = (const float*)d_in[10];
    const float* W2   = (const float*)d_in[11];
    const float* b2   = (const float*)d_in[12];
    const float* ln1g = (const float*)d_in[13];
    const float* ln1b = (const float*)d_in[14];
    const float* ln2g = (const float*)d_in[15];
    const float* ln2b = (const float*)d_in[16];

    char* ws = (char*)d_ws;
    const size_t MB = 1024 * 1024;
    bf16* WTq  = (bf16*)(ws + 0 * MB);   // [1024][1024] — WTq/WTk/WTv contiguous = fused [3072][1024]
    bf16* WTk  = (bf16*)(ws + 2 * MB);
    bf16* WTv  = (bf16*)(ws + 4 * MB);
    bf16* WTo  = (bf16*)(ws + 6 * MB);
    bf16* WT1  = (bf16*)(ws + 8 * MB);   // [4096][1024]
    bf16* WT2  = (bf16*)(ws + 16 * MB);  // [1024][4096]
    bf16* hbuf = (bf16*)(ws + 24 * MB);  // h1; later h2
    bf16* VhT  = (bf16*)(ws + 24 * MB);  // aliases hbuf (h1 dead after QKV GEMM, VhT dead before LN2)
    bf16* Qh   = (bf16*)(ws + 40 * MB);  // [64][2048][64]; Kh/Vh contiguous after
    bf16* Kh   = (bf16*)(ws + 56 * MB);
    bf16* Vh   = (bf16*)(ws + 72 * MB);
    bf16* attn = (bf16*)(ws + 88 * MB);  // [8192][1024]
    bf16* ff1  = (bf16*)(ws + 40 * MB);  // aliases Qh/Kh/Vh/attn (free after O-proj)
    float* x2  = (float*)d_out;          // fp32 residual stream in d_out

    dim3 tb(32, 8);
    transpose_cast<<<dim3(32, 32),  tb, 0, stream>>>(Wq, WTq, 1024, 1024);
    transpose_cast<<<dim3(32, 32),  tb, 0, stream>>>(Wk, WTk, 1024, 1024);
    transpose_cast<<<dim3(32, 32),  tb, 0, stream>>>(Wv, WTv, 1024, 1024);
    transpose_cast<<<dim3(32, 32),  tb, 0, stream>>>(Wo, WTo, 1024, 1024);
    transpose_cast<<<dim3(128, 32), tb, 0, stream>>>(W1, WT1, 1024, 4096);
    transpose_cast<<<dim3(32, 128), tb, 0, stream>>>(W2, WT2, 4096, 1024);

    ln_kernel<<<NTOK, 256, 0, stream>>>(x, ln1g, ln1b, hbuf);

    // fused QKV: N=3072, Q pre-scaled by QSCALE in epilogue
    gemm_bf16<0><<<dim3(24, 64), 256, 0, stream>>>(hbuf, WTq, bq, bk, bv, nullptr, Qh, NTOK, 3072, 1024);

    transpose_v<<<dim3(32, 64), 256, 0, stream>>>(Vh, VhT);

    attn_kernel<<<dim3(64, 16), 256, 0, stream>>>(Qh, Kh, VhT, attn);

    gemm_bf16<1><<<dim3(8, 64), 256, 0, stream>>>(attn, WTo, bo, nullptr, nullptr, x, x2, NTOK, 1024, 1024);

    ln_kernel<<<NTOK, 256, 0, stream>>>(x2, ln2g, ln2b, hbuf);

    gemm_bf16<2><<<dim3(32, 64), 256, 0, stream>>>(hbuf, WT1, b1, nullptr, nullptr, nullptr, ff1, NTOK, 4096, 1024);
    gemm_bf16<1><<<dim3(8, 64),  256, 0, stream>>>(ff1, WT2, b2, nullptr, nullptr, x2, x2, NTOK, 1024, 4096);
}

// Round 5
// 531.707 us; speedup vs baseline: 1.1228x; 1.0426x over previous
//
#include <hip/hip_runtime.h>
#include <hip/hip_bf16.h>

typedef __bf16 bf16;
typedef __attribute__((ext_vector_type(8))) __bf16 bf16x8;
typedef __attribute__((ext_vector_type(4))) float f32x4;

#define D_MODEL 1024
#define NHEADS  16
#define DK      64
#define DFF     4096
#define BATCH   4
#define SEQ     2048
#define NTOK    (BATCH*SEQ)   // 8192
#define QSCALE  0.18033688011112042f   // 0.125 * log2(e)

__device__ __forceinline__ void gload16(const bf16* g, bf16* l) {
    __builtin_amdgcn_global_load_lds((const __attribute__((address_space(1))) void*)g,
                                     (__attribute__((address_space(3))) void*)l, 16, 0, 0);
}

// ---------------------------------------------------------------- transpose+cast (4x 1024^2 fused on z)
__global__ __launch_bounds__(256) void transpose_cast4(
    const float* __restrict__ W0, const float* __restrict__ W1,
    const float* __restrict__ W2, const float* __restrict__ W3,
    bf16* __restrict__ T0, bf16* __restrict__ T1,
    bf16* __restrict__ T2, bf16* __restrict__ T3)
{
    const int z = blockIdx.z;
    const float* W = (z == 0) ? W0 : (z == 1) ? W1 : (z == 2) ? W2 : W3;
    bf16*       Wt = (z == 0) ? T0 : (z == 1) ? T1 : (z == 2) ? T2 : T3;
    const int K = 1024, N = 1024;
    __shared__ float tile[32][33];
    const int tx = threadIdx.x, ty = threadIdx.y;
    const int n0 = blockIdx.x * 32, k0 = blockIdx.y * 32;
#pragma unroll
    for (int i = 0; i < 4; ++i)
        tile[ty + i*8][tx] = W[(size_t)(k0 + ty + i*8) * N + n0 + tx];
    __syncthreads();
#pragma unroll
    for (int i = 0; i < 4; ++i)
        Wt[(size_t)(n0 + ty + i*8) * K + k0 + tx] = (bf16)tile[tx][ty + i*8];
}

__global__ __launch_bounds__(256) void transpose_cast(
    const float* __restrict__ W, bf16* __restrict__ Wt, int K, int N)
{
    __shared__ float tile[32][33];
    const int tx = threadIdx.x, ty = threadIdx.y;
    const int n0 = blockIdx.x * 32, k0 = blockIdx.y * 32;
#pragma unroll
    for (int i = 0; i < 4; ++i)
        tile[ty + i*8][tx] = W[(size_t)(k0 + ty + i*8) * N + n0 + tx];
    __syncthreads();
#pragma unroll
    for (int i = 0; i < 4; ++i)
        Wt[(size_t)(n0 + ty + i*8) * K + k0 + tx] = (bf16)tile[tx][ty + i*8];
}

// ---------------------------------------------------------------- V head-transpose
// Vh[bh][s][64] -> VhT[bh][64][2048]
__global__ __launch_bounds__(256) void transpose_v(
    const bf16* __restrict__ V, bf16* __restrict__ VT)
{
    __shared__ bf16 t[64][72];
    const int bh = blockIdx.y;
    const int s0 = blockIdx.x * 64;
    const int r  = threadIdx.x >> 2;         // 0..63
    const int c0 = (threadIdx.x & 3) * 16;   // 0,16,32,48
    const bf16* Vb = V  + (size_t)bh * SEQ * DK;
    bf16*       Tb = VT + (size_t)bh * DK * SEQ;
#pragma unroll
    for (int i = 0; i < 2; ++i) {
        bf16x8 v = *(const bf16x8*)&Vb[(size_t)(s0 + r) * DK + c0 + i*8];
#pragma unroll
        for (int j = 0; j < 8; ++j) t[c0 + i*8 + j][r] = v[j];
    }
    __syncthreads();
#pragma unroll
    for (int i = 0; i < 2; ++i) {
        bf16x8 o;
#pragma unroll
        for (int j = 0; j < 8; ++j) o[j] = t[r][c0 + i*8 + j];
        *(bf16x8*)&Tb[(size_t)r * SEQ + s0 + c0 + i*8] = o;
    }
}

// ---------------------------------------------------------------- layernorm (fp32 in, bf16 out)
__global__ __launch_bounds__(256) void ln_kernel(
    const float* __restrict__ x, const float* __restrict__ g,
    const float* __restrict__ beta, bf16* __restrict__ out)
{
    const int row = blockIdx.x, tid = threadIdx.x;
    const f32x4* xr = (const f32x4*)(x + (size_t)row * D_MODEL);
    f32x4 v = xr[tid];
    float s  = v[0] + v[1] + v[2] + v[3];
    float s2 = v[0]*v[0] + v[1]*v[1] + v[2]*v[2] + v[3]*v[3];
#pragma unroll
    for (int off = 32; off > 0; off >>= 1) {
        s  += __shfl_down(s,  off, 64);
        s2 += __shfl_down(s2, off, 64);
    }
    __shared__ float red[8];
    const int wave = tid >> 6, lane = tid & 63;
    if (lane == 0) { red[wave] = s; red[wave + 4] = s2; }
    __syncthreads();
    if (tid == 0) {
        float a = red[0] + red[1] + red[2] + red[3];
        float c = red[4] + red[5] + red[6] + red[7];
        float mu  = a * (1.0f / D_MODEL);
        float var = c * (1.0f / D_MODEL) - mu * mu;
        red[0] = mu;
        red[1] = rsqrtf(var + 1e-5f);
    }
    __syncthreads();
    const float mu = red[0], rs = red[1];
    f32x4 gv = ((const f32x4*)g)[tid];
    f32x4 bv = ((const f32x4*)beta)[tid];
    union { bf16 h[4]; uint2 u; } o;
#pragma unroll
    for (int i = 0; i < 4; ++i) o.h[i] = (bf16)((v[i] - mu) * rs * gv[i] + bv[i]);
    *(uint2*)(out + (size_t)row * D_MODEL + tid * 4) = o.u;
}

// ---------------------------------------------------------------- bf16 GEMM, 128x128 tile, BK=32
// M-tile on blockIdx.x so A-sharing blocks land on the same XCD (linear%8 = x%8):
// A-tile fetched once per XCD's L2 instead of 8x across XCDs.
// A[M][K] bf16, Bt[N][K] bf16 (= B^T), C = A·B + bias (+epilogue)
// EPI 0: fused QKV: bias by col segment; Q pre-scaled by QSCALE; head-scatter out
// EPI 1: fp32 out = acc + bias + resid      (O-proj, FFN2)
// EPI 2: bf16 out = relu(acc + bias)        (FFN1)
template<int EPI>
__global__ __launch_bounds__(256, 2) void gemm_bf16(
    const bf16* __restrict__ A, const bf16* __restrict__ Bt,
    const float* __restrict__ bias, const float* __restrict__ bias2,
    const float* __restrict__ bias3, const float* __restrict__ resid,
    void* __restrict__ outp, int M, int N, int K)
{
    __shared__ __align__(16) bf16 As[128 * 32];
    __shared__ __align__(16) bf16 Bs[128 * 32];
    const int tid  = threadIdx.x;
    const int wave = tid >> 6, lane = tid & 63;
    const int quad = lane >> 4, l16 = lane & 15;
    const int wr = wave >> 1, wc = wave & 1;
    const int m0 = blockIdx.x * 128, n0 = blockIdx.y * 128;

    const int r0 = wave * 32 + (lane >> 2);
    const int r1 = r0 + 16;
    const int u0 = ((lane & 3) - ((r0 >> 1) & 3)) & 3;
    const int u1 = ((lane & 3) - ((r1 >> 1) & 3)) & 3;
    const bf16* gA0 = A  + (size_t)(m0 + r0) * K + u0 * 8;
    const bf16* gA1 = A  + (size_t)(m0 + r1) * K + u1 * 8;
    const bf16* gB0 = Bt + (size_t)(n0 + r0) * K + u0 * 8;
    const bf16* gB1 = Bt + (size_t)(n0 + r1) * K + u1 * 8;
    bf16* lA0 = As + wave * 1024;
    bf16* lA1 = As + wave * 1024 + 512;
    bf16* lB0 = Bs + wave * 1024;
    bf16* lB1 = Bs + wave * 1024 + 512;

    int aoff[4], boff[4];
#pragma unroll
    for (int i = 0; i < 4; ++i) {
        const int ra = wr * 64 + i * 16 + l16;
        aoff[i] = ra * 32 + ((quad + ((ra >> 1) & 3)) & 3) * 8;
        const int rb = wc * 64 + i * 16 + l16;
        boff[i] = rb * 32 + ((quad + ((rb >> 1) & 3)) & 3) * 8;
    }

    const f32x4 vzero = {0.f, 0.f, 0.f, 0.f};
    f32x4 acc[4][4];
#pragma unroll
    for (int i = 0; i < 4; ++i)
#pragma unroll
        for (int j = 0; j < 4; ++j) acc[i][j] = vzero;

    for (int k0 = 0; k0 < K; k0 += 32) {
        __syncthreads();
        gload16(gA0 + k0, lA0);
        gload16(gA1 + k0, lA1);
        gload16(gB0 + k0, lB0);
        gload16(gB1 + k0, lB1);
        __syncthreads();
        bf16x8 af[4], bfr[4];
#pragma unroll
        for (int i = 0; i < 4; ++i) af[i]  = *(const bf16x8*)&As[aoff[i]];
#pragma unroll
        for (int j = 0; j < 4; ++j) bfr[j] = *(const bf16x8*)&Bs[boff[j]];
#pragma unroll
        for (int i = 0; i < 4; ++i)
#pragma unroll
            for (int j = 0; j < 4; ++j)
                acc[i][j] = __builtin_amdgcn_mfma_f32_16x16x32_bf16(af[i], bfr[j], acc[i][j], 0, 0, 0);
    }

#pragma unroll
    for (int i = 0; i < 4; ++i) {
#pragma unroll
        for (int j = 0; j < 4; ++j) {
            const int col = n0 + wc * 64 + j * 16 + l16;
            float bcol, sc = 1.0f;
            if (EPI == 0) {
                const int seg = col >> 10;
                const float* bp = (seg == 0) ? bias : ((seg == 1) ? bias2 : bias3);
                bcol = bp[col & 1023];
                if (seg == 0) sc = QSCALE;
            } else {
                bcol = bias[col];
            }
#pragma unroll
            for (int r = 0; r < 4; ++r) {
                const int row = m0 + wr * 64 + i * 16 + quad * 4 + r;
                const float v = acc[i][j][r] + bcol;
                if (EPI == 0) {
                    const int bb = row >> 11, ss = row & (SEQ - 1);
                    const int hh = (col & 1023) >> 6, dd = col & (DK - 1);
                    const size_t seg = (size_t)(col >> 10);
                    ((bf16*)outp)[seg * 8388608 + (((size_t)(bb * NHEADS + hh)) * SEQ + ss) * DK + dd] = (bf16)(v * sc);
                } else if (EPI == 1) {
                    const size_t idx = (size_t)row * N + col;
                    ((float*)outp)[idx] = v + resid[idx];
                } else {
                    ((bf16*)outp)[(size_t)row * N + col] = (bf16)fmaxf(v, 0.f);
                }
            }
        }
    }
}

// ---------------------------------------------------------------- flash attention (causal), S^T layout
// Q/K: [B*H][S][64] bf16 (Q pre-scaled by 0.125*log2e); VT: [B*H][64][S]; out: [B][S][H*64].
// Grid (64 bh, 16): one 128-q tile per block, qt = 15 - by (long blocks dispatch first).
// bh on blockIdx.x -> all blocks of a bh land on one XCD: K/V L2-resident.
__global__ __launch_bounds__(256, 3) void attn_kernel(
    const bf16* __restrict__ Q, const bf16* __restrict__ K,
    const bf16* __restrict__ VT, bf16* __restrict__ out)
{
    const int bh = blockIdx.x;
    const int qt = 15 - (int)blockIdx.y;
    const int b = bh >> 4, h = bh & 15;
    const int tid  = threadIdx.x;
    const int wave = tid >> 6, lane = tid & 63;
    const int quad = lane >> 4, l16 = lane & 15;

    __shared__ __align__(16) bf16 smem[8192 + 8192 + 4 * 1280];
    bf16* Ks = smem;                            // [128 kv][8 units], unit-swizzled
    bf16* Vt = smem + 8192;                     // [64 d][16 units], unit-swizzled
    bf16* Pw = smem + 16384 + wave * 1280;      // per-wave [32 q][40]

    const bf16* Qb = Q  + (size_t)bh * SEQ * DK;
    const bf16* Kb = K  + (size_t)bh * SEQ * DK;
    const bf16* Vb = VT + (size_t)bh * DK * SEQ;

    int goK[4], goV[4];
    bf16 *lK[4], *lV[4];
#pragma unroll
    for (int i = 0; i < 4; ++i) {
        const int U = (wave * 4 + i) * 64 + lane;
        const int rK = U >> 3, uK = (U & 7) ^ (rK & 7);
        goK[i] = rK * DK + uK * 8;
        lK[i]  = Ks + (wave * 4 + i) * 512;
        const int rV = U >> 4, usw = U & 15;
        const int uV = (usw & 8) | ((usw & 7) ^ (rV & 7));
        goV[i] = rV * SEQ + uV * 8;
        lV[i]  = Vt + (wave * 4 + i) * 512;
    }

    const int qw = qt * 128 + wave * 32;

    bf16x8 qf[2][2];
#pragma unroll
    for (int qi = 0; qi < 2; ++qi)
#pragma unroll
        for (int kk = 0; kk < 2; ++kk)
            qf[qi][kk] = *(const bf16x8*)&Qb[(size_t)(qw + qi*16 + l16) * DK + kk*32 + quad*8];

    const f32x4 vzero = {0.f, 0.f, 0.f, 0.f};
    f32x4 Oacc[2][4];
    float m_[2], l_[2];
#pragma unroll
    for (int qi = 0; qi < 2; ++qi) {
        m_[qi] = -1.0e30f; l_[qi] = 0.f;
#pragma unroll
        for (int dj = 0; dj < 4; ++dj) Oacc[qi][dj] = vzero;
    }

    for (int t = 0; t <= qt; ++t) {
        const int kv0 = t * 128;
        __syncthreads();
#pragma unroll
        for (int i = 0; i < 4; ++i) gload16(Kb + (size_t)kv0 * DK + goK[i], lK[i]);
#pragma unroll
        for (int i = 0; i < 4; ++i) gload16(Vb + kv0 + goV[i], lV[i]);
        __syncthreads();

        f32x4 sv[8][2];
#pragma unroll
        for (int kvt = 0; kvt < 8; ++kvt) {
            const int R = kvt*16 + l16, rx = R & 7;
            bf16x8 kf0 = *(const bf16x8*)&Ks[R*64 + (quad ^ rx)*8];
            bf16x8 kf1 = *(const bf16x8*)&Ks[R*64 + ((quad + 4) ^ rx)*8];
#pragma unroll
            for (int qi = 0; qi < 2; ++qi) {
                f32x4 tacc = vzero;
                tacc = __builtin_amdgcn_mfma_f32_16x16x32_bf16(kf0, qf[qi][0], tacc, 0, 0, 0);
                tacc = __builtin_amdgcn_mfma_f32_16x16x32_bf16(kf1, qf[qi][1], tacc, 0, 0, 0);
                sv[kvt][qi] = tacc;
            }
        }

        if (t == qt) {
#pragma unroll
            for (int kvt = 0; kvt < 8; ++kvt)
#pragma unroll
                for (int qi = 0; qi < 2; ++qi)
#pragma unroll
                    for (int r = 0; r < 4; ++r) {
                        const int kv = kv0 + kvt*16 + quad*4 + r;
                        const int q  = qw + qi*16 + l16;
                        if (kv > q) sv[kvt][qi][r] = -1.0e30f;
                    }
        }

#pragma unroll
        for (int qi = 0; qi < 2; ++qi) {
            float mx = sv[0][qi][0];
#pragma unroll
            for (int kvt = 0; kvt < 8; ++kvt)
#pragma unroll
                for (int r = 0; r < 4; ++r) mx = fmaxf(mx, sv[kvt][qi][r]);
            mx = fmaxf(mx, __shfl_xor(mx, 16, 64));
            mx = fmaxf(mx, __shfl_xor(mx, 32, 64));
            const float newm  = fmaxf(m_[qi], mx);
            const float alpha = exp2f(m_[qi] - newm);
            m_[qi] = newm;
            float rs = 0.f;
#pragma unroll
            for (int kvt = 0; kvt < 8; ++kvt)
#pragma unroll
                for (int r = 0; r < 4; ++r) {
                    const float p = exp2f(sv[kvt][qi][r] - newm);
                    sv[kvt][qi][r] = p;
                    rs += p;
                }
            rs += __shfl_xor(rs, 16, 64);
            rs += __shfl_xor(rs, 32, 64);
            l_[qi] = l_[qi] * alpha + rs;
#pragma unroll
            for (int dj = 0; dj < 4; ++dj) Oacc[qi][dj] *= alpha;
        }

#pragma unroll
        for (int c2 = 0; c2 < 4; ++c2) {
#pragma unroll
            for (int qi = 0; qi < 2; ++qi)
#pragma unroll
                for (int kl = 0; kl < 2; ++kl) {
                    union { bf16 h[4]; unsigned long long u; } pk;
                    const f32x4 s = sv[c2*2 + kl][qi];
#pragma unroll
                    for (int r = 0; r < 4; ++r) pk.h[r] = (bf16)s[r];
                    *(unsigned long long*)&Pw[(qi*16 + l16)*40 + kl*16 + quad*4] = pk.u;
                }
            bf16x8 vf[4];
#pragma unroll
            for (int dj = 0; dj < 4; ++dj) {
                const int R = dj*16 + l16;
                const int u = c2*4 + quad;
                const int usw = (u & 8) | ((u & 7) ^ (R & 7));
                vf[dj] = *(const bf16x8*)&Vt[R*128 + usw*8];
            }
#pragma unroll
            for (int qi = 0; qi < 2; ++qi) {
                bf16x8 pf = *(const bf16x8*)&Pw[(qi*16 + l16)*40 + quad*8];
#pragma unroll
                for (int dj = 0; dj < 4; ++dj)
                    Oacc[qi][dj] = __builtin_amdgcn_mfma_f32_16x16x32_bf16(vf[dj], pf, Oacc[qi][dj], 0, 0, 0);
            }
        }
    }

    // epilogue: transpose O^T through per-wave LDS, b128 coalesced stores
    __syncthreads();
    bf16* Ow = smem + wave * 2304;   // [32 q][72]
#pragma unroll
    for (int qi = 0; qi < 2; ++qi) {
        const float inv = 1.0f / l_[qi];
#pragma unroll
        for (int dj = 0; dj < 4; ++dj) {
            union { bf16 h[4]; unsigned long long u; } ok;
#pragma unroll
            for (int r = 0; r < 4; ++r) ok.h[r] = (bf16)(Oacc[qi][dj][r] * inv);
            *(unsigned long long*)&Ow[(qi*16 + l16)*72 + dj*16 + quad*4] = ok.u;
        }
    }
    const int rl = lane >> 3, ul = lane & 7;
#pragma unroll
    for (int i = 0; i < 4; ++i) {
        const int row = rl + i*8;
        const int q = qw + row;
        bf16x8 o = *(const bf16x8*)&Ow[row*72 + ul*8];
        *(bf16x8*)&out[((size_t)(b*SEQ + q))*D_MODEL + h*DK + ul*8] = o;
    }
}

// ---------------------------------------------------------------- launch
extern "C" void kernel_launch(void* const* d_in, const int* in_sizes, int n_in,
                              void* d_out, int out_size, void* d_ws, size_t ws_size,
                              hipStream_t stream)
{
    const float* x    = (const float*)d_in[0];
    const float* Wq   = (const float*)d_in[1];
    const float* bq   = (const float*)d_in[2];
    const float* Wk   = (const float*)d_in[3];
    const float* bk   = (const float*)d_in[4];
    const float* Wv   = (const float*)d_in[5];
    const float* bv   = (const float*)d_in[6];
    const float* Wo   = (const float*)d_in[7];
    const float* bo   = (const float*)d_in[8];
    const float* W1   = (const float*)d_in[9];
    const float* b1   = (const float*)d_in[10];
    const float* W2   = (const float*)d_in[11];
    const float* b2   = (const float*)d_in[12];
    const float* ln1g = (const float*)d_in[13];
    const float* ln1b = (const float*)d_in[14];
    const float* ln2g = (const float*)d_in[15];
    const float* ln2b = (const float*)d_in[16];

    char* ws = (char*)d_ws;
    const size_t MB = 1024 * 1024;
    bf16* WTq  = (bf16*)(ws + 0 * MB);   // [1024][1024] — WTq/WTk/WTv contiguous = fused [3072][1024]
    bf16* WTk  = (bf16*)(ws + 2 * MB);
    bf16* WTv  = (bf16*)(ws + 4 * MB);
    bf16* WTo  = (bf16*)(ws + 6 * MB);
    bf16* WT1  = (bf16*)(ws + 8 * MB);   // [4096][1024]
    bf16* WT2  = (bf16*)(ws + 16 * MB);  // [1024][4096]
    bf16* hbuf = (bf16*)(ws + 24 * MB);  // h1; later h2
    bf16* VhT  = (bf16*)(ws + 24 * MB);  // aliases hbuf
    bf16* Qh   = (bf16*)(ws + 40 * MB);  // [64][2048][64]; Kh/Vh contiguous after
    bf16* Kh   = (bf16*)(ws + 56 * MB);
    bf16* Vh   = (bf16*)(ws + 72 * MB);
    bf16* attn = (bf16*)(ws + 88 * MB);  // [8192][1024]
    bf16* ff1  = (bf16*)(ws + 40 * MB);  // aliases Qh/Kh/Vh/attn
    float* x2  = (float*)d_out;          // fp32 residual stream in d_out

    dim3 tb(32, 8);
    transpose_cast4<<<dim3(32, 32, 4), tb, 0, stream>>>(Wq, Wk, Wv, Wo, WTq, WTk, WTv, WTo);
    transpose_cast<<<dim3(128, 32), tb, 0, stream>>>(W1, WT1, 1024, 4096);
    transpose_cast<<<dim3(32, 128), tb, 0, stream>>>(W2, WT2, 4096, 1024);

    ln_kernel<<<NTOK, 256, 0, stream>>>(x, ln1g, ln1b, hbuf);

    // fused QKV: N=3072, Q pre-scaled by QSCALE in epilogue; M-tiles on x
    gemm_bf16<0><<<dim3(64, 24), 256, 0, stream>>>(hbuf, WTq, bq, bk, bv, nullptr, Qh, NTOK, 3072, 1024);

    transpose_v<<<dim3(32, 64), 256, 0, stream>>>(Vh, VhT);

    attn_kernel<<<dim3(64, 16), 256, 0, stream>>>(Qh, Kh, VhT, attn);

    gemm_bf16<1><<<dim3(64, 8), 256, 0, stream>>>(attn, WTo, bo, nullptr, nullptr, x, x2, NTOK, 1024, 1024);

    ln_kernel<<<NTOK, 256, 0, stream>>>(x2, ln2g, ln2b, hbuf);

    gemm_bf16<2><<<dim3(64, 32), 256, 0, stream>>>(hbuf, WT1, b1, nullptr, nullptr, nullptr, ff1, NTOK, 4096, 1024);
    gemm_bf16<1><<<dim3(64, 8),  256, 0, stream>>>(ff1, WT2, b2, nullptr, nullptr, x2, x2, NTOK, 1024, 4096);
}

// Round 6
// 519.152 us; speedup vs baseline: 1.1500x; 1.0242x over previous
//
#include <hip/hip_runtime.h>
#include <hip/hip_bf16.h>

typedef __bf16 bf16;
typedef __attribute__((ext_vector_type(8))) __bf16 bf16x8;
typedef __attribute__((ext_vector_type(4))) float f32x4;

#define D_MODEL 1024
#define NHEADS  16
#define DK      64
#define DFF     4096
#define BATCH   4
#define SEQ     2048
#define NTOK    (BATCH*SEQ)   // 8192
#define QSCALE  0.18033688011112042f   // 0.125 * log2(e)

__device__ __forceinline__ void gload16(const bf16* g, bf16* l) {
    __builtin_amdgcn_global_load_lds((const __attribute__((address_space(1))) void*)g,
                                     (__attribute__((address_space(3))) void*)l, 16, 0, 0);
}

// ---------------------------------------------------------------- transpose+cast (4x 1024^2 fused on z)
__global__ __launch_bounds__(256) void transpose_cast4(
    const float* __restrict__ W0, const float* __restrict__ W1,
    const float* __restrict__ W2, const float* __restrict__ W3,
    bf16* __restrict__ T0, bf16* __restrict__ T1,
    bf16* __restrict__ T2, bf16* __restrict__ T3)
{
    const int z = blockIdx.z;
    const float* W = (z == 0) ? W0 : (z == 1) ? W1 : (z == 2) ? W2 : W3;
    bf16*       Wt = (z == 0) ? T0 : (z == 1) ? T1 : (z == 2) ? T2 : T3;
    const int K = 1024, N = 1024;
    __shared__ float tile[32][33];
    const int tx = threadIdx.x, ty = threadIdx.y;
    const int n0 = blockIdx.x * 32, k0 = blockIdx.y * 32;
#pragma unroll
    for (int i = 0; i < 4; ++i)
        tile[ty + i*8][tx] = W[(size_t)(k0 + ty + i*8) * N + n0 + tx];
    __syncthreads();
#pragma unroll
    for (int i = 0; i < 4; ++i)
        Wt[(size_t)(n0 + ty + i*8) * K + k0 + tx] = (bf16)tile[tx][ty + i*8];
}

__global__ __launch_bounds__(256) void transpose_cast(
    const float* __restrict__ W, bf16* __restrict__ Wt, int K, int N)
{
    __shared__ float tile[32][33];
    const int tx = threadIdx.x, ty = threadIdx.y;
    const int n0 = blockIdx.x * 32, k0 = blockIdx.y * 32;
#pragma unroll
    for (int i = 0; i < 4; ++i)
        tile[ty + i*8][tx] = W[(size_t)(k0 + ty + i*8) * N + n0 + tx];
    __syncthreads();
#pragma unroll
    for (int i = 0; i < 4; ++i)
        Wt[(size_t)(n0 + ty + i*8) * K + k0 + tx] = (bf16)tile[tx][ty + i*8];
}

// ---------------------------------------------------------------- V head-transpose
// Vh[bh][s][64] -> VhT[bh][64][2048]
__global__ __launch_bounds__(256) void transpose_v(
    const bf16* __restrict__ V, bf16* __restrict__ VT)
{
    __shared__ bf16 t[64][72];
    const int bh = blockIdx.y;
    const int s0 = blockIdx.x * 64;
    const int r  = threadIdx.x >> 2;         // 0..63
    const int c0 = (threadIdx.x & 3) * 16;   // 0,16,32,48
    const bf16* Vb = V  + (size_t)bh * SEQ * DK;
    bf16*       Tb = VT + (size_t)bh * DK * SEQ;
#pragma unroll
    for (int i = 0; i < 2; ++i) {
        bf16x8 v = *(const bf16x8*)&Vb[(size_t)(s0 + r) * DK + c0 + i*8];
#pragma unroll
        for (int j = 0; j < 8; ++j) t[c0 + i*8 + j][r] = v[j];
    }
    __syncthreads();
#pragma unroll
    for (int i = 0; i < 2; ++i) {
        bf16x8 o;
#pragma unroll
        for (int j = 0; j < 8; ++j) o[j] = t[r][c0 + i*8 + j];
        *(bf16x8*)&Tb[(size_t)r * SEQ + s0 + c0 + i*8] = o;
    }
}

// ---------------------------------------------------------------- layernorm (fp32 in, bf16 out)
__global__ __launch_bounds__(256) void ln_kernel(
    const float* __restrict__ x, const float* __restrict__ g,
    const float* __restrict__ beta, bf16* __restrict__ out)
{
    const int row = blockIdx.x, tid = threadIdx.x;
    const f32x4* xr = (const f32x4*)(x + (size_t)row * D_MODEL);
    f32x4 v = xr[tid];
    float s  = v[0] + v[1] + v[2] + v[3];
    float s2 = v[0]*v[0] + v[1]*v[1] + v[2]*v[2] + v[3]*v[3];
#pragma unroll
    for (int off = 32; off > 0; off >>= 1) {
        s  += __shfl_down(s,  off, 64);
        s2 += __shfl_down(s2, off, 64);
    }
    __shared__ float red[8];
    const int wave = tid >> 6, lane = tid & 63;
    if (lane == 0) { red[wave] = s; red[wave + 4] = s2; }
    __syncthreads();
    if (tid == 0) {
        float a = red[0] + red[1] + red[2] + red[3];
        float c = red[4] + red[5] + red[6] + red[7];
        float mu  = a * (1.0f / D_MODEL);
        float var = c * (1.0f / D_MODEL) - mu * mu;
        red[0] = mu;
        red[1] = rsqrtf(var + 1e-5f);
    }
    __syncthreads();
    const float mu = red[0], rs = red[1];
    f32x4 gv = ((const f32x4*)g)[tid];
    f32x4 bv = ((const f32x4*)beta)[tid];
    union { bf16 h[4]; uint2 u; } o;
#pragma unroll
    for (int i = 0; i < 4; ++i) o.h[i] = (bf16)((v[i] - mu) * rs * gv[i] + bv[i]);
    *(uint2*)(out + (size_t)row * D_MODEL + tid * 4) = o.u;
}

// ---------------------------------------------------------------- bf16 GEMM, 128x128 tile, BK=32
// M-tile on blockIdx.x so A-sharing blocks land on the same XCD.
// EPI 0: fused QKV head-scatter (Q pre-scaled); EPI 1: fp32 +bias+resid; EPI 2: relu bf16
template<int EPI>
__global__ __launch_bounds__(256, 2) void gemm_bf16(
    const bf16* __restrict__ A, const bf16* __restrict__ Bt,
    const float* __restrict__ bias, const float* __restrict__ bias2,
    const float* __restrict__ bias3, const float* __restrict__ resid,
    void* __restrict__ outp, int M, int N, int K)
{
    __shared__ __align__(16) bf16 As[128 * 32];
    __shared__ __align__(16) bf16 Bs[128 * 32];
    const int tid  = threadIdx.x;
    const int wave = tid >> 6, lane = tid & 63;
    const int quad = lane >> 4, l16 = lane & 15;
    const int wr = wave >> 1, wc = wave & 1;
    const int m0 = blockIdx.x * 128, n0 = blockIdx.y * 128;

    const int r0 = wave * 32 + (lane >> 2);
    const int r1 = r0 + 16;
    const int u0 = ((lane & 3) - ((r0 >> 1) & 3)) & 3;
    const int u1 = ((lane & 3) - ((r1 >> 1) & 3)) & 3;
    const bf16* gA0 = A  + (size_t)(m0 + r0) * K + u0 * 8;
    const bf16* gA1 = A  + (size_t)(m0 + r1) * K + u1 * 8;
    const bf16* gB0 = Bt + (size_t)(n0 + r0) * K + u0 * 8;
    const bf16* gB1 = Bt + (size_t)(n0 + r1) * K + u1 * 8;
    bf16* lA0 = As + wave * 1024;
    bf16* lA1 = As + wave * 1024 + 512;
    bf16* lB0 = Bs + wave * 1024;
    bf16* lB1 = Bs + wave * 1024 + 512;

    int aoff[4], boff[4];
#pragma unroll
    for (int i = 0; i < 4; ++i) {
        const int ra = wr * 64 + i * 16 + l16;
        aoff[i] = ra * 32 + ((quad + ((ra >> 1) & 3)) & 3) * 8;
        const int rb = wc * 64 + i * 16 + l16;
        boff[i] = rb * 32 + ((quad + ((rb >> 1) & 3)) & 3) * 8;
    }

    const f32x4 vzero = {0.f, 0.f, 0.f, 0.f};
    f32x4 acc[4][4];
#pragma unroll
    for (int i = 0; i < 4; ++i)
#pragma unroll
        for (int j = 0; j < 4; ++j) acc[i][j] = vzero;

    for (int k0 = 0; k0 < K; k0 += 32) {
        __syncthreads();
        gload16(gA0 + k0, lA0);
        gload16(gA1 + k0, lA1);
        gload16(gB0 + k0, lB0);
        gload16(gB1 + k0, lB1);
        __syncthreads();
        bf16x8 af[4], bfr[4];
#pragma unroll
        for (int i = 0; i < 4; ++i) af[i]  = *(const bf16x8*)&As[aoff[i]];
#pragma unroll
        for (int j = 0; j < 4; ++j) bfr[j] = *(const bf16x8*)&Bs[boff[j]];
#pragma unroll
        for (int i = 0; i < 4; ++i)
#pragma unroll
            for (int j = 0; j < 4; ++j)
                acc[i][j] = __builtin_amdgcn_mfma_f32_16x16x32_bf16(af[i], bfr[j], acc[i][j], 0, 0, 0);
    }

#pragma unroll
    for (int i = 0; i < 4; ++i) {
#pragma unroll
        for (int j = 0; j < 4; ++j) {
            const int col = n0 + wc * 64 + j * 16 + l16;
            float bcol, sc = 1.0f;
            if (EPI == 0) {
                const int seg = col >> 10;
                const float* bp = (seg == 0) ? bias : ((seg == 1) ? bias2 : bias3);
                bcol = bp[col & 1023];
                if (seg == 0) sc = QSCALE;
            } else {
                bcol = bias[col];
            }
#pragma unroll
            for (int r = 0; r < 4; ++r) {
                const int row = m0 + wr * 64 + i * 16 + quad * 4 + r;
                const float v = acc[i][j][r] + bcol;
                if (EPI == 0) {
                    const int bb = row >> 11, ss = row & (SEQ - 1);
                    const int hh = (col & 1023) >> 6, dd = col & (DK - 1);
                    const size_t seg = (size_t)(col >> 10);
                    ((bf16*)outp)[seg * 8388608 + (((size_t)(bb * NHEADS + hh)) * SEQ + ss) * DK + dd] = (bf16)(v * sc);
                } else if (EPI == 1) {
                    const size_t idx = (size_t)row * N + col;
                    ((float*)outp)[idx] = v + resid[idx];
                } else {
                    ((bf16*)outp)[(size_t)row * N + col] = (bf16)fmaxf(v, 0.f);
                }
            }
        }
    }
}

// ---------------------------------------------------------------- flash attention (causal), S^T layout
// Q/K: [B*H][S][64] bf16 (Q pre-scaled by 0.125*log2e); VT: [B*H][64][S]; out: [B][S][H*64].
// Grid (64 bh, 8 pair): block does qt = 15-pair then qt = pair  => 17 kv-tiles, perfectly balanced,
// all 512 blocks resident (2/CU). K/V double-buffered in LDS with async prefetch issued at the top
// of each tile (right after the barrier) so the next barrier's vmcnt(0) drain is ~free.
__global__ __launch_bounds__(256, 2) void attn_kernel(
    const bf16* __restrict__ Q, const bf16* __restrict__ K,
    const bf16* __restrict__ VT, bf16* __restrict__ out)
{
    const int bh = blockIdx.x;
    const int b = bh >> 4, h = bh & 15;
    const int tid  = threadIdx.x;
    const int wave = tid >> 6, lane = tid & 63;
    const int quad = lane >> 4, l16 = lane & 15;

    // K: [2][128][64] @ 0, V^T: [2][64][128] @ 16384, Pw: 4 waves x [32][36] @ 32768
    __shared__ __align__(16) bf16 smem[32768 + 4 * 1152];
    bf16* Pw = smem + 32768 + wave * 1152;

    const bf16* Qb = Q  + (size_t)bh * SEQ * DK;
    const bf16* Kb = K  + (size_t)bh * SEQ * DK;
    const bf16* Vb = VT + (size_t)bh * DK * SEQ;

    // staging lane constants (swizzled, contiguous lane-order for global_load_lds)
    int goK[4], goV[4], lo[4];
#pragma unroll
    for (int i = 0; i < 4; ++i) {
        const int U = (wave * 4 + i) * 64 + lane;
        const int rK = U >> 3, uK = (U & 7) ^ (rK & 7);
        goK[i] = rK * DK + uK * 8;
        const int rV = U >> 4, usw = U & 15;
        const int uV = (usw & 8) | ((usw & 7) ^ (rV & 7));
        goV[i] = rV * SEQ + uV * 8;
        lo[i]  = (wave * 4 + i) * 512;
    }

    auto stage = [&](int buf, int t) {
        const bf16* kp = Kb + (size_t)(t * 128) * DK;
        const bf16* vp = Vb + t * 128;
        bf16* kb = smem + buf * 8192;
        bf16* vb = smem + 16384 + buf * 8192;
#pragma unroll
        for (int i = 0; i < 4; ++i) gload16(kp + goK[i], kb + lo[i]);
#pragma unroll
        for (int i = 0; i < 4; ++i) gload16(vp + goV[i], vb + lo[i]);
    };

    const f32x4 vzero = {0.f, 0.f, 0.f, 0.f};
    int g = 0;
    stage(0, 0);   // preload phase-0 tile 0

    for (int phase = 0; phase < 2; ++phase) {
        const int qt = phase ? (int)blockIdx.y : 15 - (int)blockIdx.y;
        const int qw = qt * 128 + wave * 32;

        // Q fragments (B-operand: n=q=l16, k=d=quad*8+i)
        bf16x8 qf[2][2];
#pragma unroll
        for (int qi = 0; qi < 2; ++qi)
#pragma unroll
            for (int kk = 0; kk < 2; ++kk)
                qf[qi][kk] = *(const bf16x8*)&Qb[(size_t)(qw + qi*16 + l16) * DK + kk*32 + quad*8];

        f32x4 Oacc[2][4];
        float m_[2], l_[2];
#pragma unroll
        for (int qi = 0; qi < 2; ++qi) {
            m_[qi] = -1.0e30f; l_[qi] = 0.f;
#pragma unroll
            for (int dj = 0; dj < 4; ++dj) Oacc[qi][dj] = vzero;
        }

        for (int t = 0; t <= qt; ++t, ++g) {
            const int cur = g & 1;
            __syncthreads();                       // publishes buf[cur]
            if (t < qt)            stage(cur ^ 1, t + 1);   // prefetch next kv tile
            else if (phase == 0)   stage(cur ^ 1, 0);       // bridge to phase 1
            const bf16* kb = smem + cur * 8192;
            const bf16* vb = smem + 16384 + cur * 8192;
            const int kv0 = t * 128;

            // S^T = K·Q^T
            f32x4 sv[8][2];
#pragma unroll
            for (int kvt = 0; kvt < 8; ++kvt) {
                const int R = kvt*16 + l16, rx = R & 7;
                bf16x8 kf0 = *(const bf16x8*)&kb[R*64 + (quad ^ rx)*8];
                bf16x8 kf1 = *(const bf16x8*)&kb[R*64 + (((quad + 4) & 7) ^ rx)*8];
#pragma unroll
                for (int qi = 0; qi < 2; ++qi) {
                    f32x4 tacc = vzero;
                    tacc = __builtin_amdgcn_mfma_f32_16x16x32_bf16(kf0, qf[qi][0], tacc, 0, 0, 0);
                    tacc = __builtin_amdgcn_mfma_f32_16x16x32_bf16(kf1, qf[qi][1], tacc, 0, 0, 0);
                    sv[kvt][qi] = tacc;
                }
            }

            if (t == qt) {   // diagonal: causal mask
#pragma unroll
                for (int kvt = 0; kvt < 8; ++kvt)
#pragma unroll
                    for (int qi = 0; qi < 2; ++qi)
#pragma unroll
                        for (int r = 0; r < 4; ++r) {
                            const int kv = kv0 + kvt*16 + quad*4 + r;
                            const int q  = qw + qi*16 + l16;
                            if (kv > q) sv[kvt][qi][r] = -1.0e30f;
                        }
            }

            // online softmax per q-column, base-2
#pragma unroll
            for (int qi = 0; qi < 2; ++qi) {
                float mx = sv[0][qi][0];
#pragma unroll
                for (int kvt = 0; kvt < 8; ++kvt)
#pragma unroll
                    for (int r = 0; r < 4; ++r) mx = fmaxf(mx, sv[kvt][qi][r]);
                mx = fmaxf(mx, __shfl_xor(mx, 16, 64));
                mx = fmaxf(mx, __shfl_xor(mx, 32, 64));
                const float newm  = fmaxf(m_[qi], mx);
                const float alpha = exp2f(m_[qi] - newm);
                m_[qi] = newm;
                float rs = 0.f;
#pragma unroll
                for (int kvt = 0; kvt < 8; ++kvt)
#pragma unroll
                    for (int r = 0; r < 4; ++r) {
                        const float p = exp2f(sv[kvt][qi][r] - newm);
                        sv[kvt][qi][r] = p;
                        rs += p;
                    }
                rs += __shfl_xor(rs, 16, 64);
                rs += __shfl_xor(rs, 32, 64);
                l_[qi] = l_[qi] * alpha + rs;
#pragma unroll
                for (int dj = 0; dj < 4; ++dj) Oacc[qi][dj] *= alpha;
            }

            // O^T += V^T·P^T in 32-kv chunks; P relayout via per-wave LDS (stride 36)
#pragma unroll
            for (int c2 = 0; c2 < 4; ++c2) {
#pragma unroll
                for (int qi = 0; qi < 2; ++qi)
#pragma unroll
                    for (int kl = 0; kl < 2; ++kl) {
                        union { bf16 h[4]; unsigned long long u; } pk;
                        const f32x4 s = sv[c2*2 + kl][qi];
#pragma unroll
                        for (int r = 0; r < 4; ++r) pk.h[r] = (bf16)s[r];
                        *(unsigned long long*)&Pw[(qi*16 + l16)*36 + kl*16 + quad*4] = pk.u;
                    }
                bf16x8 vf[4];
#pragma unroll
                for (int dj = 0; dj < 4; ++dj) {
                    const int R = dj*16 + l16;
                    const int u = c2*4 + quad;
                    const int usw = (u & 8) | ((u & 7) ^ (R & 7));
                    vf[dj] = *(const bf16x8*)&vb[R*128 + usw*8];
                }
#pragma unroll
                for (int qi = 0; qi < 2; ++qi) {
                    bf16x8 pf = *(const bf16x8*)&Pw[(qi*16 + l16)*36 + quad*8];
#pragma unroll
                    for (int dj = 0; dj < 4; ++dj)
                        Oacc[qi][dj] = __builtin_amdgcn_mfma_f32_16x16x32_bf16(vf[dj], pf, Oacc[qi][dj], 0, 0, 0);
                }
            }
        }

        // phase epilogue through private Pw (no barrier): chunked [32 q][32 d] halves
        const float inv0 = 1.0f / l_[0], inv1 = 1.0f / l_[1];
#pragma unroll
        for (int dh = 0; dh < 2; ++dh) {
#pragma unroll
            for (int qi = 0; qi < 2; ++qi) {
                const float inv = qi ? inv1 : inv0;
#pragma unroll
                for (int djl = 0; djl < 2; ++djl) {
                    const int dj = dh*2 + djl;
                    union { bf16 h[4]; unsigned long long u; } ok;
#pragma unroll
                    for (int r = 0; r < 4; ++r) ok.h[r] = (bf16)(Oacc[qi][dj][r] * inv);
                    *(unsigned long long*)&Pw[(qi*16 + l16)*36 + djl*16 + quad*4] = ok.u;
                }
            }
            const int row = lane >> 1;
#pragma unroll
            for (int it = 0; it < 2; ++it) {
                const int grp = (lane & 1) + 2*it;
                bf16x8 o = *(const bf16x8*)&Pw[row*36 + grp*8];
                *(bf16x8*)&out[((size_t)(b*SEQ + qw - wave*32 + wave*32 + row))*D_MODEL + h*DK + dh*32 + grp*8] = o;
            }
        }
    }
}

// ---------------------------------------------------------------- launch
extern "C" void kernel_launch(void* const* d_in, const int* in_sizes, int n_in,
                              void* d_out, int out_size, void* d_ws, size_t ws_size,
                              hipStream_t stream)
{
    const float* x    = (const float*)d_in[0];
    const float* Wq   = (const float*)d_in[1];
    const float* bq   = (const float*)d_in[2];
    const float* Wk   = (const float*)d_in[3];
    const float* bk   = (const float*)d_in[4];
    const float* Wv   = (const float*)d_in[5];
    const float* bv   = (const float*)d_in[6];
    const float* Wo   = (const float*)d_in[7];
    const float* bo   = (const float*)d_in[8];
    const float* W1   = (const float*)d_in[9];
    const float* b1   = (const float*)d_in[10];
    const float* W2   = (const float*)d_in[11];
    const float* b2   = (const float*)d_in[12];
    const float* ln1g = (const float*)d_in[13];
    const float* ln1b = (const float*)d_in[14];
    const float* ln2g = (const float*)d_in[15];
    const float* ln2b = (const float*)d_in[16];

    char* ws = (char*)d_ws;
    const size_t MB = 1024 * 1024;
    bf16* WTq  = (bf16*)(ws + 0 * MB);   // [1024][1024] — WTq/WTk/WTv contiguous = fused [3072][1024]
    bf16* WTk  = (bf16*)(ws + 2 * MB);
    bf16* WTv  = (bf16*)(ws + 4 * MB);
    bf16* WTo  = (bf16*)(ws + 6 * MB);
    bf16* WT1  = (bf16*)(ws + 8 * MB);   // [4096][1024]
    bf16* WT2  = (bf16*)(ws + 16 * MB);  // [1024][4096]
    bf16* hbuf = (bf16*)(ws + 24 * MB);  // h1; later h2
    bf16* VhT  = (bf16*)(ws + 24 * MB);  // aliases hbuf
    bf16* Qh   = (bf16*)(ws + 40 * MB);  // [64][2048][64]; Kh/Vh contiguous after
    bf16* Kh   = (bf16*)(ws + 56 * MB);
    bf16* Vh   = (bf16*)(ws + 72 * MB);
    bf16* attn = (bf16*)(ws + 88 * MB);  // [8192][1024]
    bf16* ff1  = (bf16*)(ws + 40 * MB);  // aliases Qh/Kh/Vh/attn
    float* x2  = (float*)d_out;          // fp32 residual stream in d_out

    dim3 tb(32, 8);
    transpose_cast4<<<dim3(32, 32, 4), tb, 0, stream>>>(Wq, Wk, Wv, Wo, WTq, WTk, WTv, WTo);
    transpose_cast<<<dim3(128, 32), tb, 0, stream>>>(W1, WT1, 1024, 4096);
    transpose_cast<<<dim3(32, 128), tb, 0, stream>>>(W2, WT2, 4096, 1024);

    ln_kernel<<<NTOK, 256, 0, stream>>>(x, ln1g, ln1b, hbuf);

    // fused QKV: N=3072, Q pre-scaled by QSCALE in epilogue; M-tiles on x
    gemm_bf16<0><<<dim3(64, 24), 256, 0, stream>>>(hbuf, WTq, bq, bk, bv, nullptr, Qh, NTOK, 3072, 1024);

    transpose_v<<<dim3(32, 64), 256, 0, stream>>>(Vh, VhT);

    attn_kernel<<<dim3(64, 8), 256, 0, stream>>>(Qh, Kh, VhT, attn);

    gemm_bf16<1><<<dim3(64, 8), 256, 0, stream>>>(attn, WTo, bo, nullptr, nullptr, x, x2, NTOK, 1024, 1024);

    ln_kernel<<<NTOK, 256, 0, stream>>>(x2, ln2g, ln2b, hbuf);

    gemm_bf16<2><<<dim3(64, 32), 256, 0, stream>>>(hbuf, WT1, b1, nullptr, nullptr, nullptr, ff1, NTOK, 4096, 1024);
    gemm_bf16<1><<<dim3(64, 8),  256, 0, stream>>>(ff1, WT2, b2, nullptr, nullptr, x2, x2, NTOK, 1024, 4096);
}